// Round 4
// baseline (817.517 us; speedup 1.0000x reference)
//
#include <hip/hip_runtime.h>

// ======================================================================
// Involution net: 3 x (1x1 conv + dynamic-kernel apply w/ batch BN) + FC
// B=1024, fp32 reference.
//
// R7: latency/occupancy round. R6 counters: all 4 heavy kernels ~150us,
// all pipes <16%, occupancy 10-21% -> latency-bound. Fixes:
//  * every heavy grid 1024 -> 2048 (split per-block work in half):
//    p1 splits the 16 h-tiles, f2 splits the 64 pixels, f3 splits M=512,
//    f4 splits channels (partial FC atomically summed into zeroed out).
//  * halved accumulators drop VGPR buckets (p1 acc 64->32, f2 64->32,
//    f3 32->16 regs) -> more waves/SIMD.
//  * p1 staging: scattered 64B gathers (1.28TB/s) -> coalesced float4
//    row staging into LDS fp32 with source-side XOR swizzle (col^16 per
//    row-group-parity) so the per-lane fragment gather is <=2-way bank
//    aliased (free); convert to split-bf16 once per element in LDS.
// Arithmetic identical to R6 (which passed, absmax 0.0625).
// ======================================================================

typedef __attribute__((ext_vector_type(8))) short short8v;   // 8 bf16 bit-patterns
typedef __attribute__((ext_vector_type(4))) float f32x4;

__device__ __forceinline__ unsigned short f2bf_rne(float x) {
    unsigned u = __float_as_uint(x);
    unsigned r = u + 0x7FFFu + ((u >> 16) & 1u);
    return (unsigned short)(r >> 16);
}
__device__ __forceinline__ float bf2f(unsigned short h) {
    return __uint_as_float(((unsigned)h) << 16);
}

static constexpr size_t OFF_WCAT1 = 0;        // unused by MFMA path (kept)
static constexpr size_t OFF_WCAT2 = 25600;
static constexpr size_t OFF_WCAT3 = 41984;
static constexpr size_t OFF_SUM1  = 107520;
static constexpr size_t OFF_SQS1  = 107584;
static constexpr size_t OFF_SUM2  = 107648;
static constexpr size_t OFF_SQS2  = 107776;
static constexpr size_t OFF_SUM3  = 107904;
static constexpr size_t OFF_SQS3  = 108160;
static constexpr size_t OFF_XI1   = 108416;     // 16777216 floats (also xi3)
static constexpr size_t OFF_RPRE1 = 16885632;   //  4194304 floats (also rpre3)
static constexpr size_t OFF_XI2   = 21079936;   //  8388608 floats
static constexpr size_t OFF_RPRE2 = 29468544;   //  2097152 floats -> end 31565696
static constexpr size_t OFF_APKH  = OFF_XI2;            // aliases xi2 (dead then)
static constexpr size_t OFF_APKL  = OFF_XI2 + 14336;

// ---------------- weight concat+transpose prep + stat zero + out zero ----------------
__global__ void prep_all(const float* __restrict__ wi1, const float* __restrict__ wr1,
                         const float* __restrict__ wi2, const float* __restrict__ wr2,
                         const float* __restrict__ wi3, const float* __restrict__ wr3,
                         float* __restrict__ ws, float* __restrict__ outz) {
    int e = blockIdx.x * 256 + threadIdx.x;
    if (e < 16384) outz[e] = 0.f;                 // out accumulates f4 partials
    if (e >= 108416) return;
    if (e >= 107520) { ws[e] = 0.f; return; }     // BN stat accumulators
    const float* wi; const float* wr; float* wt; int cin, cout;
    if (e < 25600)      { wi = wi1; wr = wr1; wt = ws + OFF_WCAT1; cin = 200; cout = 64; }
    else if (e < 41984) { e -= 25600; wi = wi2; wr = wr2; wt = ws + OFF_WCAT2; cin = 64;  cout = 128; }
    else                { e -= 41984; wi = wi3; wr = wr3; wt = ws + OFF_WCAT3; cin = 128; cout = 256; }
    int M = 2 * cout, c = e / M, m = e % M;
    wt[e] = (m < cout) ? wi[m * cin + c] : wr[(m - cout) * cin + c];
}

// ---------------- A-fragment packing for p1_l1 MFMA (unchanged) ----------------
__global__ void prep_apk(const float* __restrict__ wi1, const float* __restrict__ wr1,
                         unsigned short* __restrict__ ah, unsigned short* __restrict__ al) {
    int e = blockIdx.x * 256 + threadIdx.x;
    if (e >= 28672) return;
    int v  = e & 7;
    int l  = (e >> 3) & 63;
    int mt = (e >> 9) & 7;
    int ck = e >> 12;
    int c = 32 * ck + ((l >> 4) << 3) + v;
    int m = 16 * mt + (l & 15);
    float wv = 0.f;
    if (c < 200) wv = (m < 64) ? wi1[m * 200 + c] : wr1[(m - 64) * 200 + c];
    unsigned short h = f2bf_rne(wv);
    ah[e] = h;
    al[e] = f2bf_rne(wv - bf2f(h));
}

// ---------------- P1 layer 1 via split-bf16 MFMA, 2048 blocks ----------------
// block = (b, half): half owns h-tiles nt in [8*half, 8*half+8), cols n0=128*half.
// 512 thr = 8 waves; wave w owns m-tile w (rows 16w..16w+15), 8 nt tiles.
// C/D: col = lane&15 (n within tile), row = 4*(lane>>4)+reg (m within tile).
__global__ __launch_bounds__(512) void p1_l1_mfma(
    const float* __restrict__ x,      // [B][200][256]
    const unsigned short* __restrict__ aHiG,
    const unsigned short* __restrict__ aLoG,
    float* __restrict__ xi,           // [B][64][256]
    float* __restrict__ rpre,         // [B][64][64]
    float* __restrict__ ssum, float* __restrict__ ssqs)
{
    __shared__ float xf[4096];                          // [32][128] fp32, src-swizzled
    __shared__ __align__(16) unsigned short bHi[4096];  // 512 slots x 8 bf16
    __shared__ __align__(16) unsigned short bLo[4096];
    const int tid = threadIdx.x;
    const int b = blockIdx.x >> 1, half = blockIdx.x & 1;
    const int lane = tid & 63, w = tid >> 6;
    const int n0 = 128 * half;
    const float* xb = x + (size_t)b * 200 * 256;

    f32x4 acc[8];
    #pragma unroll
    for (int i = 0; i < 8; ++i) acc[i] = f32x4{0.f, 0.f, 0.f, 0.f};

    // staging geometry: 1024 float4 slots = [32 rows][32 col4]; this thread
    // owns (row0, col4) and (row0+16, col4). Source col swizzled: col4 ^ s
    // with s = ((row>>3)&1)<<2 (rows 8-15/24-31 read the other 16-col half)
    // -> the fragment gather below lands on disjoint bank halves.
    const int row0 = tid >> 5;            // 0..15
    const int col4 = tid & 31;
    const int c4x  = col4 ^ (((row0 >> 3) & 1) << 2);   // row0+16 has same bit3
    const float* src0 = xb + n0 + 4 * c4x + (size_t)row0 * 256;
    const float* src1 = src0 + (size_t)16 * 256;

    auto ldg = [&](const float* p, int c) -> float4 {
        return (c < 200) ? *(const float4*)p : float4{0.f, 0.f, 0.f, 0.f};
    };

    // fragment gather geometry (slot = tid): lane-group g reads rows 8g+j,
    // col (16*ntl + l&15) ^ (g&1)<<4  (matches the staging swizzle).
    const int ntl_s = tid >> 6, l_s = tid & 63, g_s = l_s >> 4;
    const int qx = (16 * ntl_s + (l_s & 15)) ^ ((g_s & 1) << 4);
    const int grow = 8 * g_s;

    float4 r0 = ldg(src0, row0), r1 = ldg(src1, row0 + 16);

    for (int ck = 0; ck < 7; ++ck) {
        ((float4*)xf)[row0 * 32 + col4] = r0;
        ((float4*)xf)[(row0 + 16) * 32 + col4] = r1;
        __syncthreads();                                  // xf ready
        if (ck < 6) {
            int c0n = 32 * (ck + 1);
            r0 = ldg(src0 + (size_t)c0n * 256, c0n + row0);
            r1 = ldg(src1 + (size_t)c0n * 256, c0n + row0 + 16);
        }
        // gather 8 elems, split to bf16 hi/lo, write own frag slot
        {
            unsigned short h[8], g8[8];
            #pragma unroll
            for (int j = 0; j < 8; ++j) {
                float v = xf[(grow + j) * 128 + qx];
                h[j] = f2bf_rne(v);
                g8[j] = f2bf_rne(v - bf2f(h[j]));
            }
            uint4 ph, pl;
            ph.x = (unsigned)h[0] | ((unsigned)h[1] << 16);
            ph.y = (unsigned)h[2] | ((unsigned)h[3] << 16);
            ph.z = (unsigned)h[4] | ((unsigned)h[5] << 16);
            ph.w = (unsigned)h[6] | ((unsigned)h[7] << 16);
            pl.x = (unsigned)g8[0] | ((unsigned)g8[1] << 16);
            pl.y = (unsigned)g8[2] | ((unsigned)g8[3] << 16);
            pl.z = (unsigned)g8[4] | ((unsigned)g8[5] << 16);
            pl.w = (unsigned)g8[6] | ((unsigned)g8[7] << 16);
            *(uint4*)(bHi + (size_t)tid * 8) = ph;
            *(uint4*)(bLo + (size_t)tid * 8) = pl;
        }
        __syncthreads();                                  // frags ready
        const size_t abase = ((size_t)(ck * 8 + w) * 64 + lane) * 8;
        short8v aH = *(const short8v*)(aHiG + abase);
        short8v aL = *(const short8v*)(aLoG + abase);
        #pragma unroll
        for (int nt = 0; nt < 8; ++nt) {
            short8v bH = *(const short8v*)(bHi + ((size_t)(nt * 64 + lane)) * 8);
            short8v bL = *(const short8v*)(bLo + ((size_t)(nt * 64 + lane)) * 8);
            acc[nt] = __builtin_amdgcn_mfma_f32_16x16x32_bf16(aH, bH, acc[nt], 0, 0, 0);
            acc[nt] = __builtin_amdgcn_mfma_f32_16x16x32_bf16(aH, bL, acc[nt], 0, 0, 0);
            acc[nt] = __builtin_amdgcn_mfma_f32_16x16x32_bf16(aL, bH, acc[nt], 0, 0, 0);
        }
        // next xf overwrite happens after the next top-of-loop barrier
    }

    // epilogue. local nt = h - 8*half; n = 128*half + 16*nt + col.
    const int g = lane >> 4, col = lane & 15;
    if (w < 4) {
        float* xr = xi + ((size_t)b * 64 + 16 * w + 4 * g) * 256 + n0 + col;
        #pragma unroll
        for (int r = 0; r < 4; ++r)
            #pragma unroll
            for (int nt = 0; nt < 8; ++nt)
                xr[(size_t)r * 256 + nt * 16] = acc[nt][r];
    } else {
        #pragma unroll
        for (int r = 0; r < 4; ++r) {
            const int mr = 16 * (w - 4) + 4 * g + r;
            float pv[4], s1 = 0.f, s2 = 0.f;
            #pragma unroll
            for (int p = 0; p < 4; ++p) {
                float a0 = acc[2 * p][r], a1 = acc[2 * p + 1][r];
                float pp = 0.25f * (a0 + __shfl_xor(a0, 1) + a1 + __shfl_xor(a1, 1));
                pv[p] = pp; s1 += pp; s2 += pp * pp;
            }
            if ((col & 1) == 0) {
                float* rp = rpre + ((size_t)b * 64 + mr) * 64 + (col >> 1);
                #pragma unroll
                for (int p = 0; p < 4; ++p) rp[(4 * half + p) * 8] = pv[p];
            }
            s1 += __shfl_xor(s1, 2); s2 += __shfl_xor(s2, 2);
            s1 += __shfl_xor(s1, 4); s2 += __shfl_xor(s2, 4);
            s1 += __shfl_xor(s1, 8); s2 += __shfl_xor(s2, 8);
            if (col == 0) { atomicAdd(ssum + mr, s1); atomicAdd(ssqs + mr, s2); }
        }
    }
}

// ---------------- F2: p3(layer1) + p1_l2, 2048 blocks (pixel split) ----------------
// block = (b, nh): owns q in [32*nh, 32*nh+32). Phase A restricted to q-half;
// phase B GEMM M=256 (full), N=32, K=64 (Xl half resident).
__global__ __launch_bounds__(256) void f2_kernel(
    const float* __restrict__ xi1,    // [B][64][256]
    const float* __restrict__ rpre1,  // [B][64][64]
    const float* __restrict__ ssum1, const float* __restrict__ ssqs1,
    const float* __restrict__ gamma1, const float* __restrict__ beta1,
    const float* __restrict__ wspan1, // [4][64]
    const float* __restrict__ wT2,    // [64][256]
    float* __restrict__ xi2,          // [B][128][64]
    float* __restrict__ rpre2,        // [B][128][16]
    float* __restrict__ ssum2, float* __restrict__ ssqs2)
{
    __shared__ float sc[64], sh[64];
    __shared__ float kl[4 * 32];
    __shared__ float rws[4096];   // rl[64][32] in phase A, Ws chunk [16][256] in phase B
    __shared__ float Xl[2048];    // out1[b][*][q-half] = [64][32]
    const int tid = threadIdx.x;
    const int b = blockIdx.x >> 1, nh = blockIdx.x & 1;

    if (tid < 64) {
        float mean = ssum1[tid] * (1.f / 65536.f);
        float var  = ssqs1[tid] * (1.f / 65536.f) - mean * mean;
        float s    = gamma1[tid] * rsqrtf(var + 1e-5f);
        sc[tid] = s; sh[tid] = beta1[tid] - mean * s;
    }
    __syncthreads();
    const float* rp1 = rpre1 + (size_t)b * 4096;
    for (int e = tid; e < 2048; e += 256) {
        int o = e >> 5, ql = e & 31;
        rws[e] = fmaxf(fmaf(sc[o], rp1[o * 64 + nh * 32 + ql], sh[o]), 0.f);
    }
    __syncthreads();
    if (tid < 128) {   // kernel-gen: 4 kk x 32 q
        int kk = tid >> 5, ql = tid & 31;
        float s = 0.f;
        #pragma unroll
        for (int o = 0; o < 64; ++o)
            s = fmaf(wspan1[kk * 64 + o], rws[(o << 5) + ql], s);
        kl[tid] = s;
    }
    __syncthreads();
    const float* xb1 = xi1 + (size_t)b * 64 * 256;
    for (int e = tid; e < 2048; e += 256) {
        int o = e >> 5, ql = e & 31, q = nh * 32 + ql, ho = q >> 3, wo = q & 7;
        const float* p = xb1 + ((size_t)(o * 16 + 2 * ho)) * 16 + 2 * wo;
        float2 t  = *(const float2*)p;
        float2 bo = *(const float2*)(p + 16);
        Xl[e] = kl[ql] * t.x + kl[32 + ql] * t.y + kl[64 + ql] * bo.x + kl[96 + ql] * bo.y;
    }
    __syncthreads();

    // phase B: rows tm*4+i (xi) & 128+tm*4+i (red), cols nh*32 + tn*4..+3
    const int tn = tid & 7, tm = tid >> 3;
    float acc[8][4];
    #pragma unroll
    for (int i = 0; i < 8; ++i)
        #pragma unroll
        for (int j = 0; j < 4; ++j) acc[i][j] = 0.f;

    for (int c0 = 0; c0 < 64; c0 += 16) {
        for (int e = tid * 4; e < 4096; e += 1024)
            *(float4*)(rws + e) = *(const float4*)(wT2 + (size_t)c0 * 256 + e);
        __syncthreads();
        #pragma unroll
        for (int c = 0; c < 16; ++c) {
            float4 xa = *(const float4*)(Xl + (c0 + c) * 32 + tn * 4);
            float4 wa = *(const float4*)(rws + c * 256 + tm * 4);
            float4 wb = *(const float4*)(rws + c * 256 + 128 + tm * 4);
            float xf[4] = {xa.x, xa.y, xa.z, xa.w};
            float wf[8] = {wa.x, wa.y, wa.z, wa.w, wb.x, wb.y, wb.z, wb.w};
            #pragma unroll
            for (int i = 0; i < 8; ++i)
                #pragma unroll
                for (int j = 0; j < 4; ++j)
                    acc[i][j] = fmaf(wf[i], xf[j], acc[i][j]);
        }
        __syncthreads();
    }

    const int gr = tm * 4;
    #pragma unroll
    for (int i = 0; i < 4; ++i) {
        float* dst = xi2 + ((size_t)b * 128 + gr + i) * 64 + nh * 32 + tn * 4;
        *(float4*)dst = float4{acc[i][0], acc[i][1], acc[i][2], acc[i][3]};
    }
    // pool: q = nh*32 + tn*4 + j; ho = 4*nh + (tn>>1); wo pairs are (j0,j1),(j2,j3)
    const bool val = (tn & 2) == 0;
    #pragma unroll
    for (int i = 4; i < 8; ++i) {
        const int mr = gr + i - 4;
        float hp0 = acc[i][0] + acc[i][1], hp1 = acc[i][2] + acc[i][3];
        float p0 = 0.25f * (hp0 + __shfl_xor(hp0, 2));
        float p1 = 0.25f * (hp1 + __shfl_xor(hp1, 2));
        float s1 = val ? (p0 + p1) : 0.f;
        float s2 = val ? (p0 * p0 + p1 * p1) : 0.f;
        if (val) {
            const int wo = (tn & 1) * 2, ho = tn >> 2;   // ho in 0..1 within half
            float* rp = rpre2 + ((size_t)b * 128 + mr) * 16;
            *(float2*)(rp + (2 * nh + ho) * 4 + wo) = float2{p0, p1};
        }
        #pragma unroll
        for (int off = 1; off <= 4; off <<= 1) {
            s1 += __shfl_xor(s1, off); s2 += __shfl_xor(s2, off);
        }
        if (tn == 0) { atomicAdd(ssum2 + mr, s1); atomicAdd(ssqs2 + mr, s2); }
    }
}

// ---------------- F3: p3(layer2) + p1_l3, 2048 blocks (M split) ----------------
// block = (b, mh): phase A duplicated (full Xl needed as K); phase B rows
// xi [128*mh,128*mh+128) and red likewise; per-thread 2 xi + 2 red rows.
__global__ __launch_bounds__(256) void f3_kernel(
    const float* __restrict__ xi2,    // [B][128][64]
    const float* __restrict__ rpre2,  // [B][128][16]
    const float* __restrict__ ssum2, const float* __restrict__ ssqs2,
    const float* __restrict__ gamma2, const float* __restrict__ beta2,
    const float* __restrict__ wspan2, // [4][128]
    const float* __restrict__ wT3,    // [128][512]
    float* __restrict__ xi3,          // [B][256][16]
    float* __restrict__ rpre3,        // [B][256][16]
    float* __restrict__ ssum3, float* __restrict__ ssqs3)
{
    __shared__ float sc[128], sh[128];
    __shared__ float kl[4 * 16];
    __shared__ float rws[4096];   // rl[128][16] in phase A, Ws chunk [16][256] in phase B
    __shared__ float Xl[2048];    // out2[b] = [128][16]
    const int tid = threadIdx.x;
    const int b = blockIdx.x >> 1, mh = blockIdx.x & 1;

    if (tid < 128) {
        float mean = ssum2[tid] * (1.f / 16384.f);
        float var  = ssqs2[tid] * (1.f / 16384.f) - mean * mean;
        float s    = gamma2[tid] * rsqrtf(var + 1e-5f);
        sc[tid] = s; sh[tid] = beta2[tid] - mean * s;
    }
    __syncthreads();
    const float* rp2 = rpre2 + (size_t)b * 2048;
    for (int e = tid; e < 2048; e += 256) {
        int o = e >> 4;
        rws[e] = fmaxf(fmaf(sc[o], rp2[e], sh[o]), 0.f);
    }
    __syncthreads();
    if (tid < 64) {
        int kk = tid >> 4, q = tid & 15;
        float s = 0.f;
        #pragma unroll
        for (int o = 0; o < 128; ++o)
            s = fmaf(wspan2[kk * 128 + o], rws[(o << 4) + q], s);
        kl[tid] = s;
    }
    __syncthreads();
    const float* xb2 = xi2 + (size_t)b * 128 * 64;
    for (int e = tid; e < 2048; e += 256) {
        int o = e >> 4, q = e & 15, ho = q >> 2, wo = q & 3;
        const float* p = xb2 + ((size_t)(o * 8 + 2 * ho)) * 8 + 2 * wo;
        float2 t  = *(const float2*)p;
        float2 bo = *(const float2*)(p + 8);
        Xl[e] = kl[q] * t.x + kl[16 + q] * t.y + kl[32 + q] * bo.x + kl[48 + q] * bo.y;
    }
    __syncthreads();

    // phase B: tn = tid&3 (cols tn*4), tm = tid>>2 in 0..63; rows 2tm,2tm+1
    const int tn = tid & 3, tm = tid >> 2;
    float acc[4][4];
    #pragma unroll
    for (int i = 0; i < 4; ++i)
        #pragma unroll
        for (int j = 0; j < 4; ++j) acc[i][j] = 0.f;

    for (int c0 = 0; c0 < 128; c0 += 16) {
        // stage wT3 M-half: rws[16][256]; cols 0..127 = xi rows mh*128+ml,
        // cols 128..255 = red rows 256+mh*128+ml
        for (int e4 = tid; e4 < 1024; e4 += 256) {
            int c = e4 >> 6, ml4 = e4 & 63;
            int m4 = (ml4 < 32) ? (mh * 32 + ml4) : (64 + mh * 32 + (ml4 - 32));
            ((float4*)rws)[e4] = ((const float4*)(wT3 + (size_t)(c0 + c) * 512))[m4];
        }
        __syncthreads();
        #pragma unroll
        for (int c = 0; c < 16; ++c) {
            float4 xa = *(const float4*)(Xl + (c0 + c) * 16 + tn * 4);
            float2 wa = *(const float2*)(rws + c * 256 + 2 * tm);
            float2 wb = *(const float2*)(rws + c * 256 + 128 + 2 * tm);
            float xfv[4] = {xa.x, xa.y, xa.z, xa.w};
            float wf[4] = {wa.x, wa.y, wb.x, wb.y};
            #pragma unroll
            for (int i = 0; i < 4; ++i)
                #pragma unroll
                for (int j = 0; j < 4; ++j)
                    acc[i][j] = fmaf(wf[i], xfv[j], acc[i][j]);
        }
        __syncthreads();
    }

    #pragma unroll
    for (int i = 0; i < 2; ++i) {
        int row = mh * 128 + 2 * tm + i;
        *(float4*)(xi3 + ((size_t)b * 256 + row) * 16 + tn * 4) =
            float4{acc[i][0], acc[i][1], acc[i][2], acc[i][3]};
    }
    #pragma unroll
    for (int i = 2; i < 4; ++i) {
        const int mr = mh * 128 + 2 * tm + (i - 2);
        *(float4*)(rpre3 + ((size_t)b * 256 + mr) * 16 + tn * 4) =
            float4{acc[i][0], acc[i][1], acc[i][2], acc[i][3]};
        float s1 = acc[i][0] + acc[i][1] + acc[i][2] + acc[i][3];
        float s2 = acc[i][0] * acc[i][0] + acc[i][1] * acc[i][1]
                 + acc[i][2] * acc[i][2] + acc[i][3] * acc[i][3];
        s1 += __shfl_xor(s1, 1); s2 += __shfl_xor(s2, 1);
        s1 += __shfl_xor(s1, 2); s2 += __shfl_xor(s2, 2);
        if (tn == 0) { atomicAdd(ssum3 + mr, s1); atomicAdd(ssqs3 + mr, s2); }
    }
}

// ---------------- F4: p3(layer3) + FC, 2048 blocks (channel split) ----------------
// block = (b, oh): applies 3x3 and FC-partial over channels [128*oh,+128);
// kernel-gen (full-channel reduction) duplicated; partials atomicAdd'ed
// into out (zeroed by prep_all); bfc added once by oh==0.
__global__ __launch_bounds__(256) void f4_kernel(
    const float* __restrict__ xi3,    // [B][256][16]
    const float* __restrict__ rpre3,  // [B][256][16]
    const float* __restrict__ ssum3, const float* __restrict__ ssqs3,
    const float* __restrict__ gamma3, const float* __restrict__ beta3,
    const float* __restrict__ wspan3, // [9][256]
    const float* __restrict__ wfc,    // [16][4096]
    const float* __restrict__ bfc,    // [16]
    float* __restrict__ out)          // [B][16], pre-zeroed
{
    __shared__ float sc[256], sh[256];
    __shared__ float kl[9 * 16];
    __shared__ float xil[2048];       // xi3[b] channel-half
    __shared__ float rh[4096];        // rl (full, for kernel-gen) then h-half in [0,2048)
    __shared__ float red[4][16];
    const int tid = threadIdx.x;
    const int b = blockIdx.x >> 1, oh = blockIdx.x & 1;

    {
        float mean = ssum3[tid] * (1.f / 16384.f);
        float var  = ssqs3[tid] * (1.f / 16384.f) - mean * mean;
        float s    = gamma3[tid] * rsqrtf(var + 1e-5f);
        sc[tid] = s; sh[tid] = beta3[tid] - mean * s;
    }
    const float* xb3 = xi3 + (size_t)b * 4096 + (size_t)oh * 2048;
    for (int e = tid; e < 512; e += 256)
        ((float4*)xil)[e] = ((const float4*)xb3)[e];
    __syncthreads();

    const float* rp3 = rpre3 + (size_t)b * 4096;
    for (int e = tid; e < 4096; e += 256) {
        int o = e >> 4;
        rh[e] = fmaxf(fmaf(sc[o], rp3[e], sh[o]), 0.f);
    }
    __syncthreads();
    if (tid < 144) {   // kernel-gen (full 256-channel reduction, duplicated)
        int kk = tid >> 4, q = tid & 15;
        float s = 0.f;
        #pragma unroll
        for (int o = 0; o < 256; ++o)
            s = fmaf(wspan3[kk * 256 + o], rh[(o << 4) + q], s);
        kl[tid] = s;
    }
    __syncthreads();
    // apply 3x3 pad=1 on 4x4 for this channel half; overwrite rh[0..2048)
    for (int e = tid; e < 2048; e += 256) {
        int ol = e >> 4, q = e & 15, ho = q >> 2, wo = q & 3;
        float v = 0.f;
        const float* xo = xil + (ol << 4);
        #pragma unroll
        for (int ki = 0; ki < 3; ++ki) {
            int h = ho + ki - 1;
            if (h < 0 || h >= 4) continue;
            #pragma unroll
            for (int kj = 0; kj < 3; ++kj) {
                int w = wo + kj - 1;
                if (w < 0 || w >= 4) continue;
                v = fmaf(kl[(ki * 3 + kj) * 16 + q], xo[h * 4 + w], v);
            }
        }
        rh[e] = v;
    }
    __syncthreads();

    // FC partial over features [oh*2048, oh*2048+2048)
    float acc[16];
    #pragma unroll
    for (int n = 0; n < 16; ++n) acc[n] = 0.f;
    const float* wfb = wfc + (size_t)oh * 2048;
    for (int i = 0; i < 8; ++i) {
        int f = tid + i * 256;
        float hv = rh[f];
        #pragma unroll
        for (int n = 0; n < 16; ++n)
            acc[n] = fmaf(hv, wfb[n * 4096 + f], acc[n]);
    }
    #pragma unroll
    for (int n = 0; n < 16; ++n) {
        float v = acc[n];
        #pragma unroll
        for (int off = 1; off < 64; off <<= 1) v += __shfl_xor(v, off);
        acc[n] = v;
    }
    const int wave = tid >> 6, lane = tid & 63;
    if (lane == 0) {
        #pragma unroll
        for (int n = 0; n < 16; ++n) red[wave][n] = acc[n];
    }
    __syncthreads();
    if (tid < 16) {
        float part = red[0][tid] + red[1][tid] + red[2][tid] + red[3][tid];
        if (oh == 0) part += bfc[tid];
        atomicAdd(out + (size_t)b * 16 + tid, part);
    }
}

// ---------------- launch ----------------
extern "C" void kernel_launch(void* const* d_in, const int* in_sizes, int n_in,
                              void* d_out, int out_size, void* d_ws, size_t ws_size,
                              hipStream_t stream) {
    const float* x    = (const float*)d_in[0];
    const float* Wi1  = (const float*)d_in[1];
    const float* Wr1  = (const float*)d_in[2];
    const float* g1   = (const float*)d_in[3];
    const float* be1  = (const float*)d_in[4];
    const float* Wsp1 = (const float*)d_in[5];
    const float* Wi2  = (const float*)d_in[6];
    const float* Wr2  = (const float*)d_in[7];
    const float* g2   = (const float*)d_in[8];
    const float* be2  = (const float*)d_in[9];
    const float* Wsp2 = (const float*)d_in[10];
    const float* Wi3  = (const float*)d_in[11];
    const float* Wr3  = (const float*)d_in[12];
    const float* g3   = (const float*)d_in[13];
    const float* be3  = (const float*)d_in[14];
    const float* Wsp3 = (const float*)d_in[15];
    const float* Wfc  = (const float*)d_in[16];
    const float* bfc  = (const float*)d_in[17];
    float* out = (float*)d_out;
    float* ws  = (float*)d_ws;

    float* wcat2 = ws + OFF_WCAT2;
    float* wcat3 = ws + OFF_WCAT3;
    float* sum1 = ws + OFF_SUM1; float* sqs1 = ws + OFF_SQS1;
    float* sum2 = ws + OFF_SUM2; float* sqs2 = ws + OFF_SQS2;
    float* sum3 = ws + OFF_SUM3; float* sqs3 = ws + OFF_SQS3;
    float* xi1   = ws + OFF_XI1;
    float* rpre1 = ws + OFF_RPRE1;
    float* xi2   = ws + OFF_XI2;
    float* rpre2 = ws + OFF_RPRE2;
    float* xi3   = ws + OFF_XI1;     // layer-1 region dead after f2 (kernel boundary)
    float* rpre3 = ws + OFF_RPRE1;
    unsigned short* apkh = (unsigned short*)(ws + OFF_APKH);  // aliases xi2 (dead now)
    unsigned short* apkl = (unsigned short*)(ws + OFF_APKL);

    prep_all<<<424, 256, 0, stream>>>(Wi1, Wr1, Wi2, Wr2, Wi3, Wr3, ws, out);
    prep_apk<<<112, 256, 0, stream>>>(Wi1, Wr1, apkh, apkl);

    p1_l1_mfma<<<2048, 512, 0, stream>>>(x, apkh, apkl, xi1, rpre1, sum1, sqs1);

    f2_kernel<<<2048, 256, 0, stream>>>(xi1, rpre1, sum1, sqs1, g1, be1, Wsp1,
                                        wcat2, xi2, rpre2, sum2, sqs2);

    f3_kernel<<<2048, 256, 0, stream>>>(xi2, rpre2, sum2, sqs2, g2, be2, Wsp2,
                                        wcat3, xi3, rpre3, sum3, sqs3);

    f4_kernel<<<2048, 256, 0, stream>>>(xi3, rpre3, sum3, sqs3, g3, be3, Wsp3,
                                        Wfc, bfc, out);
}